// Round 11
// baseline (164.104 us; speedup 1.0000x reference)
//
#include <hip/hip_runtime.h>
#include <hip/hip_bf16.h>
#include <math.h>

#define HEADS 8
#define DH 64
#define SEQ 2048
#define BATCH 2
#define DMODEL 512
#define INNER 512
#define WIN 8

typedef unsigned short ushort_t;
typedef __attribute__((ext_vector_type(8))) __bf16 bf16x8;
typedef __attribute__((ext_vector_type(8))) unsigned short u16x8;
typedef __attribute__((ext_vector_type(4))) float f32x4;

__device__ inline float bf2f(ushort_t u) {
    unsigned v = ((unsigned)u) << 16; float f; __builtin_memcpy(&f, &v, 4); return f;
}
__device__ inline ushort_t f2bf(float f) {
    __hip_bfloat16 h = __float2bfloat16(f); ushort_t u; __builtin_memcpy(&u, &h, 2); return u;
}
__device__ inline float fast_exp2(float x) { return __builtin_amdgcn_exp2f(x); }
// ushort-index XOR swizzle for [*][64] bf16 tiles (byte ^= (row&7)<<4)
__device__ inline int swz_idx(int row, int col) { return ((row << 6) | col) ^ ((row & 7) << 3); }

__device__ inline bf16x8 ld_frag(const ushort_t* lds, int row, int col) {
    u16x8 v = *(const u16x8*)&lds[swz_idx(row, col)];
    return __builtin_bit_cast(bf16x8, v);
}
__device__ inline f32x4 mfma16(bf16x8 a, bf16x8 b, f32x4 c) {
    return __builtin_amdgcn_mfma_f32_16x16x32_bf16(a, b, c, 0, 0, 0);
}
__device__ inline void gload16(const void* g, void* l) {
    __builtin_amdgcn_global_load_lds(
        (const __attribute__((address_space(1))) unsigned int*)g,
        (__attribute__((address_space(3))) unsigned int*)l, 16, 0, 0);
}

// ---------------- fused: cast x/W to bf16 + zero z/counter  |  sn1: v' = W u ------------
__global__ __launch_bounds__(256) void fused_cast_sn1(const float* __restrict__ x,
                                                      const float* __restrict__ Wq,
                                                      const float* __restrict__ Wo,
                                                      const float* __restrict__ uq,
                                                      const float* __restrict__ uo,
                                                      ushort_t* __restrict__ xb,
                                                      ushort_t* __restrict__ wqb,
                                                      ushort_t* __restrict__ wob,
                                                      float* __restrict__ zbuf,
                                                      float* __restrict__ v1,
                                                      float* __restrict__ v2) {
    const int b = blockIdx.x;
    if (b < 1536) {
        const int gid = b * 256 + threadIdx.x;   // 393216 threads over cast work
        const float* src; ushort_t* dst; int g;
        if (gid < 262144)      { src = x;  dst = xb;  g = gid; }
        else if (gid < 360448) { src = Wq; dst = wqb; g = gid - 262144; }
        else                   { src = Wo; dst = wob; g = gid - 360448; }
        float4 a = *(const float4*)&src[(size_t)g * 8];
        float4 c = *(const float4*)&src[(size_t)g * 8 + 4];
        u16x8 o;
        o[0] = f2bf(a.x); o[1] = f2bf(a.y); o[2] = f2bf(a.z); o[3] = f2bf(a.w);
        o[4] = f2bf(c.x); o[5] = f2bf(c.y); o[6] = f2bf(c.z); o[7] = f2bf(c.w);
        *(u16x8*)&dst[(size_t)g * 8] = o;
        if (gid < 1032) zbuf[gid] = 0.f;   // z1(512) + z2(512) + counter
    } else {
        const int lane = threadIdx.x & 63, w = threadIdx.x >> 6;
        const int r = (b - 1536) * 4 + w;  // 0..2047
        const float* W; const float* u; float* vout; int rr;
        if (r < 1536) { W = Wq; u = uq; vout = v1; rr = r; }
        else          { W = Wo; u = uo; vout = v2; rr = r - 1536; }
        float4 w0 = *(const float4*)&W[(size_t)rr * 512 + lane * 8];
        float4 w1 = *(const float4*)&W[(size_t)rr * 512 + lane * 8 + 4];
        float4 u0 = *(const float4*)&u[lane * 8];
        float4 u1 = *(const float4*)&u[lane * 8 + 4];
        float dot = w0.x * u0.x + w0.y * u0.y + w0.z * u0.z + w0.w * u0.w +
                    w1.x * u1.x + w1.y * u1.y + w1.z * u1.z + w1.w * u1.w;
#pragma unroll
        for (int off = 1; off < 64; off <<= 1) dot += __shfl_xor(dot, off, 64);
        if (lane == 0) vout[rr] = dot;
    }
}

// ---------------- GEMM1 (blocks 0-767) + sn2/sn3 (blocks 768-895) ----------------------
// gemm: qkv_unscaled = xb @ wqb^T, 128x64 tile; scatter q/k:[bh][s][d] v:[bh][d][s]
// sn:   z = W^T v' (atomics) ; last block computes scales = sigma*||v'||/||z||
__global__ __launch_bounds__(256) void gemm_qkv_sn(const ushort_t* __restrict__ A,
                                                   const ushort_t* __restrict__ B,
                                                   ushort_t* __restrict__ qkv,
                                                   const float* __restrict__ Wq,
                                                   const float* __restrict__ Wo,
                                                   const float* __restrict__ v1,
                                                   const float* __restrict__ v2,
                                                   float* __restrict__ z1,
                                                   float* __restrict__ z2,
                                                   float* __restrict__ counter,
                                                   const float* __restrict__ sq,
                                                   const float* __restrict__ so,
                                                   float* __restrict__ scales) {
    constexpr int K = DMODEL;
    __shared__ ushort_t As[8 * 128 * 8];
    __shared__ ushort_t Bs[8 * 64 * 8];
    __shared__ float red[256];
    __shared__ int is_last;
    const int t = threadIdx.x;

    if (blockIdx.x >= 768) {
        // ---- sn2 + sn3 tail ----
        const int b = blockIdx.x - 768;               // 0..127
        {
            const float* W; const float* v; float* z; int r0;
            if (b < 96) { W = Wq; v = v1; z = z1; r0 = b * 16; }
            else        { W = Wo; v = v2; z = z2; r0 = (b - 96) * 16; }
            float a0 = 0.f, a1 = 0.f;
            for (int i = 0; i < 16; ++i) {
                float vv = v[r0 + i];
                a0 += W[(size_t)(r0 + i) * 512 + t] * vv;
                a1 += W[(size_t)(r0 + i) * 512 + 256 + t] * vv;
            }
            atomicAdd(&z[t], a0);
            atomicAdd(&z[t + 256], a1);
        }
        __threadfence();
        __syncthreads();
        if (t == 0) is_last = (atomicAdd(counter, 1.0f) == 127.0f);
        __syncthreads();
        if (!is_last) return;
        __threadfence();
        for (int which = 0; which < 2; ++which) {
            const float* v = which ? v2 : v1;
            const float* z = which ? z2 : z1;
            const int R = which ? 512 : 1536;
            float n1 = 0.f;
            for (int i = t; i < R; i += 256) { float q = v[i]; n1 += q * q; }
            red[t] = n1; __syncthreads();
            for (int off = 128; off > 0; off >>= 1) { if (t < off) red[t] += red[t + off]; __syncthreads(); }
            n1 = red[0]; __syncthreads();
            float n2 = 0.f;
            for (int i = t; i < 512; i += 256) { float q = z[i]; n2 += q * q; }
            red[t] = n2; __syncthreads();
            for (int off = 128; off > 0; off >>= 1) { if (t < off) red[t] += red[t + off]; __syncthreads(); }
            if (t == 0) scales[which] = (which ? so[0] : sq[0]) * sqrtf(n1 / red[0]);
            __syncthreads();
        }
        return;
    }

    // ---- gemm ----
    const int lane = t & 63, w = t >> 6;
    const int wm = w >> 1, wn = w & 1, lg = lane >> 4, li = lane & 15;
    const int m0 = (blockIdx.x / 24) * 128, n0 = (blockIdx.x % 24) * 64;
    f32x4 acc[4][2] = {};
    for (int k0 = 0; k0 < K; k0 += 64) {
        __syncthreads();
#pragma unroll
        for (int i = 0; i < 4; ++i) {
            int j = w * 4 + i;
            int kc = j >> 1, mh = (j & 1) * 64;
            gload16(&A[(size_t)(m0 + mh + lane) * K + k0 + kc * 8], &As[(kc * 128 + mh) * 8]);
        }
#pragma unroll
        for (int i = 0; i < 2; ++i) {
            int kc = w * 2 + i;
            gload16(&B[(size_t)(n0 + lane) * K + k0 + kc * 8], &Bs[(kc * 64) * 8]);
        }
        __syncthreads();
#pragma unroll
        for (int kw = 0; kw < 2; ++kw) {
            bf16x8 af[4], bf[2];
#pragma unroll
            for (int mi = 0; mi < 4; ++mi)
                af[mi] = *(const bf16x8*)&As[((kw * 4 + lg) * 128 + wm * 64 + mi * 16 + li) * 8];
#pragma unroll
            for (int ni = 0; ni < 2; ++ni)
                bf[ni] = *(const bf16x8*)&Bs[((kw * 4 + lg) * 64 + wn * 32 + ni * 16 + li) * 8];
#pragma unroll
            for (int mi = 0; mi < 4; ++mi)
#pragma unroll
                for (int ni = 0; ni < 2; ++ni)
                    acc[mi][ni] = mfma16(af[mi], bf[ni], acc[mi][ni]);
        }
    }
    ushort_t* vT = qkv + (size_t)2 * BATCH * HEADS * SEQ * DH;
    if (n0 >= 1024) {
#pragma unroll
        for (int mi = 0; mi < 4; ++mi) {
            int base = m0 + wm * 64 + mi * 16 + lg * 4;
            int bb = base >> 11, ss = base & 2047;
#pragma unroll
            for (int ni = 0; ni < 2; ++ni) {
                int n = n0 + wn * 32 + ni * 16 + li;
                int h = (n >> 6) & 7, d0 = n & 63;
                ushort4 o;
                o.x = f2bf(acc[mi][ni][0]); o.y = f2bf(acc[mi][ni][1]);
                o.z = f2bf(acc[mi][ni][2]); o.w = f2bf(acc[mi][ni][3]);
                *(ushort4*)&vT[((size_t)((bb * HEADS + h) * DH) + d0) * SEQ + ss] = o;
            }
        }
    } else {
#pragma unroll
        for (int mi = 0; mi < 4; ++mi)
#pragma unroll
            for (int r = 0; r < 4; ++r) {
                int row = m0 + wm * 64 + mi * 16 + lg * 4 + r;
                int bb = row >> 11, ss = row & 2047;
#pragma unroll
                for (int ni = 0; ni < 2; ++ni) {
                    int n = n0 + wn * 32 + ni * 16 + li;
                    int which = n >> 9, h = (n >> 6) & 7, d0 = n & 63;
                    qkv[(size_t)which * (BATCH * HEADS * SEQ * DH) +
                        ((size_t)((bb * HEADS + h) * SEQ) + ss) * DH + d0] = f2bf(acc[mi][ni][r]);
                }
            }
    }
}

// ---------------- GEMM2: 64x64 tile, BK=64 -> 512 blocks (2/CU) -------------------------
__global__ __launch_bounds__(256) void gemm_bt_out(const ushort_t* __restrict__ A,
                                                   const ushort_t* __restrict__ B,
                                                   const float* __restrict__ scales,
                                                   const float* __restrict__ bias,
                                                   float* __restrict__ C) {
    constexpr int K = INNER;
    __shared__ ushort_t As[8 * 64 * 8];
    __shared__ ushort_t Bs[8 * 64 * 8];
    const int t = threadIdx.x, lane = t & 63, w = t >> 6;
    const int wm = w >> 1, wn = w & 1, lg = lane >> 4, li = lane & 15;
    const int m0 = blockIdx.y * 64, n0 = blockIdx.x * 64;
    f32x4 acc[2][2] = {};
    for (int k0 = 0; k0 < K; k0 += 64) {
        __syncthreads();
#pragma unroll
        for (int i = 0; i < 2; ++i) {
            int kc = w * 2 + i;
            gload16(&A[(size_t)(m0 + lane) * K + k0 + kc * 8], &As[(kc * 64) * 8]);
            gload16(&B[(size_t)(n0 + lane) * K + k0 + kc * 8], &Bs[(kc * 64) * 8]);
        }
        __syncthreads();
#pragma unroll
        for (int kw = 0; kw < 2; ++kw) {
            bf16x8 af[2], bf[2];
#pragma unroll
            for (int mi = 0; mi < 2; ++mi)
                af[mi] = *(const bf16x8*)&As[((kw * 4 + lg) * 64 + wm * 32 + mi * 16 + li) * 8];
#pragma unroll
            for (int ni = 0; ni < 2; ++ni)
                bf[ni] = *(const bf16x8*)&Bs[((kw * 4 + lg) * 64 + wn * 32 + ni * 16 + li) * 8];
#pragma unroll
            for (int mi = 0; mi < 2; ++mi)
#pragma unroll
                for (int ni = 0; ni < 2; ++ni)
                    acc[mi][ni] = mfma16(af[mi], bf[ni], acc[mi][ni]);
        }
    }
    const float sc = scales[0] * scales[1];
#pragma unroll
    for (int mi = 0; mi < 2; ++mi)
#pragma unroll
        for (int r = 0; r < 4; ++r) {
            int row = m0 + wm * 32 + mi * 16 + lg * 4 + r;
#pragma unroll
            for (int ni = 0; ni < 2; ++ni) {
                int n = n0 + wn * 32 + ni * 16 + li;
                C[(size_t)row * INNER + n] = acc[mi][ni][r] * sc + bias[n];
            }
        }
}

// ---------------- flash attention: swapped-QK MFMA, no-max softmax, split-KV, async dbuf
// S^T = mfma(K, Q): lane owns q = i0+16*wl+li (lane-constant) and k = kc*16+lg*4+r,
// so P stores are 4x ds_write_b64 (4 consecutive k) and lsum is a single scalar/lane.
__global__ __launch_bounds__(512) void attn_mfma_kernel(const ushort_t* __restrict__ qkv,
                                                        const float* __restrict__ temp,
                                                        const float* __restrict__ scales,
                                                        ushort_t* __restrict__ attn_out) {
    __shared__ ushort_t kvbuf[2 * 4 * 4096];   // 64 KB: [buf][K0,K1,V0,V1]
    __shared__ ushort_t Pl[2 * 4096];          // 16 KB (den overlays after loop)
    const int t    = threadIdx.x;
    const int lane = t & 63, w = t >> 6;
    const int g    = w >> 2, wl = w & 3;
    const int lg   = lane >> 4, li = lane & 15;
    const int bh   = blockIdx.x >> 5;
    const int i0   = (blockIdx.x & 31) * 64;
    const ushort_t* qp  = qkv;
    const ushort_t* kp  = qkv + (size_t)BATCH * HEADS * SEQ * DH;
    const ushort_t* vTp = kp  + (size_t)BATCH * HEADS * SEQ * DH;  // [bh][d][s]
    const ushort_t* kp_bh  = kp  + (size_t)bh * SEQ * DH;
    const ushort_t* vTp_bh = vTp + (size_t)bh * DH * SEQ;
    const float s0 = scales[0];
    const float st = expf(temp[0]) * s0 * s0 * 1.44269504088896340736f;  // fold log2(e)

    ushort_t* Pb = Pl + g * 4096;
    const int srw = lane >> 3;                    // row within 8-row stripe
    const int sc  = (lane & 7) ^ srw;             // inverse-swizzled source chunk

    bf16x8 aQ[2];
#pragma unroll
    for (int c = 0; c < 2; ++c) {
        u16x8 qv = *(const u16x8*)&qp[((size_t)bh * SEQ + i0 + 16 * wl + li) * DH + 32 * c + lg * 8];
        u16x8 r;
#pragma unroll
        for (int j = 0; j < 8; ++j) r[j] = f2bf(bf2f(qv[j]) * st);
        aQ[c] = __builtin_bit_cast(bf16x8, r);
    }

    float lsum = 0.f;                 // per-lane: q = i0+16*wl+li
    f32x4 oacc[4] = {};
    const int qi = i0 + 16 * wl + li;

    auto STAGE = [&](int jtn, int tbuf) {
#pragma unroll
        for (int i = 0; i < 4; ++i) {
            const int sid = i * 8 + w;
            const int bsel = sid >> 3;            // 0,1: K tiles; 2,3: V tiles
            const int srow8 = sid & 7;
            const int row = srow8 * 8 + srw;
            const ushort_t* gsrc;
            if (bsel < 2)
                gsrc = kp_bh + (size_t)(jtn * 128 + bsel * 64 + row) * DH + sc * 8;
            else
                gsrc = vTp_bh + (size_t)row * SEQ + jtn * 128 + (bsel - 2) * 64 + sc * 8;
            gload16(gsrc, &kvbuf[tbuf * 16384 + bsel * 4096 + srow8 * 512]);
        }
    };

    STAGE(0, 0);
    __syncthreads();

    int cur = 0;
    for (int jt = 0; jt < SEQ / 128; ++jt) {
        if (jt < SEQ / 128 - 1) STAGE(jt + 1, cur ^ 1);   // async, drains at barrier
        const ushort_t* Kb = kvbuf + cur * 16384 + g * 4096;
        const ushort_t* Vb = kvbuf + cur * 16384 + 8192 + g * 4096;
        const int j0 = jt * 128 + g * 64;

        // S^T = K Q^T : s[kc][r] = S[k = j0+kc*16+lg*4+r][q = qi]
        f32x4 s[4];
        __builtin_amdgcn_s_setprio(1);
#pragma unroll
        for (int kc = 0; kc < 4; ++kc) {
            bf16x8 b0 = ld_frag(Kb, kc * 16 + li, lg * 8);
            bf16x8 b1 = ld_frag(Kb, kc * 16 + li, 32 + lg * 8);
            f32x4 z = {0.f, 0.f, 0.f, 0.f};
            z = mfma16(b0, aQ[0], z);      // A = K fragment, B = Q fragment
            z = mfma16(b1, aQ[1], z);
            s[kc] = z;
        }
        __builtin_amdgcn_s_setprio(0);
        // p = masked ? 0 : exp2(s); pack 4 consecutive k per ds_write_b64
        const bool need_mask = (j0 == i0) || (j0 == i0 - 64);
#pragma unroll
        for (int kc = 0; kc < 4; ++kc) {
            float p0, p1, p2, p3;
            if (need_mask) {
                int kjb = j0 + kc * 16 + lg * 4;
                p0 = ((unsigned)(qi - kjb - 0) < (unsigned)WIN) ? 0.f : fast_exp2(s[kc][0]);
                p1 = ((unsigned)(qi - kjb - 1) < (unsigned)WIN) ? 0.f : fast_exp2(s[kc][1]);
                p2 = ((unsigned)(qi - kjb - 2) < (unsigned)WIN) ? 0.f : fast_exp2(s[kc][2]);
                p3 = ((unsigned)(qi - kjb - 3) < (unsigned)WIN) ? 0.f : fast_exp2(s[kc][3]);
            } else {
                p0 = fast_exp2(s[kc][0]); p1 = fast_exp2(s[kc][1]);
                p2 = fast_exp2(s[kc][2]); p3 = fast_exp2(s[kc][3]);
            }
            lsum += (p0 + p1) + (p2 + p3);
            ushort4 o;
            o.x = f2bf(p0); o.y = f2bf(p1); o.z = f2bf(p2); o.w = f2bf(p3);
            *(ushort4*)&Pb[swz_idx(16 * wl + li, kc * 16 + lg * 4)] = o;
        }
        // PV: O += P V
        bf16x8 aP[2];
#pragma unroll
        for (int c = 0; c < 2; ++c) aP[c] = ld_frag(Pb, 16 * wl + li, c * 32 + lg * 8);
        __builtin_amdgcn_s_setprio(1);
#pragma unroll
        for (int tt = 0; tt < 4; ++tt) {
            bf16x8 b0 = ld_frag(Vb, tt * 16 + li, lg * 8);
            bf16x8 b1 = ld_frag(Vb, tt * 16 + li, 32 + lg * 8);
            oacc[tt] = mfma16(aP[0], b0, oacc[tt]);
            oacc[tt] = mfma16(aP[1], b1, oacc[tt]);
        }
        __builtin_amdgcn_s_setprio(0);
        __syncthreads();
        cur ^= 1;
    }

    // full denominator for q = qi: reduce across the 4 lg groups
    lsum += __shfl_xor(lsum, 16, 64);
    lsum += __shfl_xor(lsum, 32, 64);
    float* den    = (float*)Pl;           // [2][64] overlay (P no longer read)
    float* O_part = (float*)kvbuf;        // 64 x 68 f32 (padded: no bank conflict)
    if (lg == 0) den[g * 64 + 16 * wl + li] = lsum;
    if (g == 1) {
#pragma unroll
        for (int r = 0; r < 4; ++r) {
            int row = 16 * wl + lg * 4 + r;
#pragma unroll
            for (int tt = 0; tt < 4; ++tt)
                O_part[row * 68 + tt * 16 + li] = oacc[tt][r];
        }
    }
    __syncthreads();
    if (g == 0) {
        const int b_ = bh >> 3, h = bh & 7;
#pragma unroll
        for (int r = 0; r < 4; ++r) {
            int row = 16 * wl + lg * 4 + r;
            float inv = 1.0f / (den[row] + den[64 + row]);
            size_t base = ((size_t)(b_ * SEQ + i0 + row)) * INNER + h * DH;
#pragma unroll
            for (int tt = 0; tt < 4; ++tt)
                attn_out[base + tt * 16 + li] =
                    f2bf((oacc[tt][r] + O_part[row * 68 + tt * 16 + li]) * inv);
        }
    }
}

extern "C" void kernel_launch(void* const* d_in, const int* in_sizes, int n_in,
                              void* d_out, int out_size, void* d_ws, size_t ws_size,
                              hipStream_t stream) {
    const float* x     = (const float*)d_in[0];
    const float* W_qkv = (const float*)d_in[1];
    const float* u_qkv = (const float*)d_in[2];
    const float* s_qkv = (const float*)d_in[3];
    const float* W_out = (const float*)d_in[4];
    const float* b_out = (const float*)d_in[5];
    const float* u_out = (const float*)d_in[6];
    const float* s_out = (const float*)d_in[7];
    const float* temp  = (const float*)d_in[8];
    float* out = (float*)d_out;

    float* scales  = (float*)d_ws;        // 2
    float* v1      = scales + 64;         // 1536
    float* v2      = v1 + 1536;           // 512
    float* z1      = v2 + 512;            // 512   <- zbuf base (z1,z2,counter zeroed by k1)
    float* z2      = z1 + 512;            // 512
    float* counter = z1 + 1024;           // 1
    ushort_t* xb    = (ushort_t*)((char*)d_ws + 16384);
    ushort_t* wqb   = xb + (size_t)2097152;
    ushort_t* wob   = wqb + (size_t)786432;
    ushort_t* qkvb  = wob + (size_t)262144;
    ushort_t* attnb = qkvb + (size_t)6291456;

    fused_cast_sn1<<<dim3(2048), dim3(256), 0, stream>>>(x, W_qkv, W_out, u_qkv, u_out,
                                                         xb, wqb, wob, z1, v1, v2);
    gemm_qkv_sn<<<dim3(896), dim3(256), 0, stream>>>(xb, wqb, qkvb, W_qkv, W_out, v1, v2,
                                                     z1, z2, counter, s_qkv, s_out, scales);
    attn_mfma_kernel<<<dim3(512), dim3(512), 0, stream>>>(qkvb, temp, scales, attnb);
    gemm_bt_out<<<dim3(8, 64), dim3(256), 0, stream>>>(attnb, wob, scales, b_out, out);
}

// Round 12
// 158.876 us; speedup vs baseline: 1.0329x; 1.0329x over previous
//
#include <hip/hip_runtime.h>
#include <hip/hip_bf16.h>
#include <math.h>

#define HEADS 8
#define DH 64
#define SEQ 2048
#define BATCH 2
#define DMODEL 512
#define INNER 512
#define WIN 8

typedef unsigned short ushort_t;
typedef __attribute__((ext_vector_type(8))) __bf16 bf16x8;
typedef __attribute__((ext_vector_type(8))) unsigned short u16x8;
typedef __attribute__((ext_vector_type(4))) float f32x4;

__device__ inline float bf2f(ushort_t u) {
    unsigned v = ((unsigned)u) << 16; float f; __builtin_memcpy(&f, &v, 4); return f;
}
__device__ inline ushort_t f2bf(float f) {
    __hip_bfloat16 h = __float2bfloat16(f); ushort_t u; __builtin_memcpy(&u, &h, 2); return u;
}
__device__ inline float fast_exp2(float x) { return __builtin_amdgcn_exp2f(x); }
// ushort-index XOR swizzle for [*][64] bf16 tiles (byte ^= (row&7)<<4)
__device__ inline int swz_idx(int row, int col) { return ((row << 6) | col) ^ ((row & 7) << 3); }

__device__ inline bf16x8 ld_frag(const ushort_t* lds, int row, int col) {
    u16x8 v = *(const u16x8*)&lds[swz_idx(row, col)];
    return __builtin_bit_cast(bf16x8, v);
}
__device__ inline f32x4 mfma16(bf16x8 a, bf16x8 b, f32x4 c) {
    return __builtin_amdgcn_mfma_f32_16x16x32_bf16(a, b, c, 0, 0, 0);
}
__device__ inline void gload16(const void* g, void* l) {
    __builtin_amdgcn_global_load_lds(
        (const __attribute__((address_space(1))) unsigned int*)g,
        (__attribute__((address_space(3))) unsigned int*)l, 16, 0, 0);
}

// ---------------- fused: cast x/W to bf16 + zero z/counter  |  sn1: v' = W u ------------
__global__ __launch_bounds__(256) void fused_cast_sn1(const float* __restrict__ x,
                                                      const float* __restrict__ Wq,
                                                      const float* __restrict__ Wo,
                                                      const float* __restrict__ uq,
                                                      const float* __restrict__ uo,
                                                      ushort_t* __restrict__ xb,
                                                      ushort_t* __restrict__ wqb,
                                                      ushort_t* __restrict__ wob,
                                                      float* __restrict__ zbuf,
                                                      float* __restrict__ v1,
                                                      float* __restrict__ v2) {
    const int b = blockIdx.x;
    if (b < 1536) {
        const int gid = b * 256 + threadIdx.x;   // 393216 threads over cast work
        const float* src; ushort_t* dst; int g;
        if (gid < 262144)      { src = x;  dst = xb;  g = gid; }
        else if (gid < 360448) { src = Wq; dst = wqb; g = gid - 262144; }
        else                   { src = Wo; dst = wob; g = gid - 360448; }
        float4 a = *(const float4*)&src[(size_t)g * 8];
        float4 c = *(const float4*)&src[(size_t)g * 8 + 4];
        u16x8 o;
        o[0] = f2bf(a.x); o[1] = f2bf(a.y); o[2] = f2bf(a.z); o[3] = f2bf(a.w);
        o[4] = f2bf(c.x); o[5] = f2bf(c.y); o[6] = f2bf(c.z); o[7] = f2bf(c.w);
        *(u16x8*)&dst[(size_t)g * 8] = o;
        if (gid < 1032) zbuf[gid] = 0.f;   // z1(512) + z2(512) + counter
    } else {
        const int lane = threadIdx.x & 63, w = threadIdx.x >> 6;
        const int r = (b - 1536) * 4 + w;  // 0..2047
        const float* W; const float* u; float* vout; int rr;
        if (r < 1536) { W = Wq; u = uq; vout = v1; rr = r; }
        else          { W = Wo; u = uo; vout = v2; rr = r - 1536; }
        float4 w0 = *(const float4*)&W[(size_t)rr * 512 + lane * 8];
        float4 w1 = *(const float4*)&W[(size_t)rr * 512 + lane * 8 + 4];
        float4 u0 = *(const float4*)&u[lane * 8];
        float4 u1 = *(const float4*)&u[lane * 8 + 4];
        float dot = w0.x * u0.x + w0.y * u0.y + w0.z * u0.z + w0.w * u0.w +
                    w1.x * u1.x + w1.y * u1.y + w1.z * u1.z + w1.w * u1.w;
#pragma unroll
        for (int off = 1; off < 64; off <<= 1) dot += __shfl_xor(dot, off, 64);
        if (lane == 0) vout[rr] = dot;
    }
}

// ---------------- GEMM1: sn blocks FIRST (0-127), gemm blocks 128-895 -------------------
// sn:   z = W^T v' (atomics); last sn block computes scales (overlaps gemm execution)
// gemm: qkv_unscaled = xb @ wqb^T, 128x64 tile, double-buffered async staging
__global__ __launch_bounds__(256) void gemm_qkv_sn(const ushort_t* __restrict__ A,
                                                   const ushort_t* __restrict__ B,
                                                   ushort_t* __restrict__ qkv,
                                                   const float* __restrict__ Wq,
                                                   const float* __restrict__ Wo,
                                                   const float* __restrict__ v1,
                                                   const float* __restrict__ v2,
                                                   float* __restrict__ z1,
                                                   float* __restrict__ z2,
                                                   float* __restrict__ counter,
                                                   const float* __restrict__ sq,
                                                   const float* __restrict__ so,
                                                   float* __restrict__ scales) {
    constexpr int K = DMODEL;
    __shared__ ushort_t As[2][8 * 128 * 8];   // 2 x 16 KB
    __shared__ ushort_t Bs[2][8 * 64 * 8];    // 2 x 8 KB
    __shared__ float red[256];
    __shared__ int is_last;
    const int t = threadIdx.x;

    if (blockIdx.x < 128) {
        // ---- sn2 + sn3 (dispatched first -> runs immediately, sn3 overlaps gemm) ----
        const int b = blockIdx.x;
        {
            const float* W; const float* v; float* z; int r0;
            if (b < 96) { W = Wq; v = v1; z = z1; r0 = b * 16; }
            else        { W = Wo; v = v2; z = z2; r0 = (b - 96) * 16; }
            float a0 = 0.f, a1 = 0.f;
            for (int i = 0; i < 16; ++i) {
                float vv = v[r0 + i];
                a0 += W[(size_t)(r0 + i) * 512 + t] * vv;
                a1 += W[(size_t)(r0 + i) * 512 + 256 + t] * vv;
            }
            atomicAdd(&z[t], a0);
            atomicAdd(&z[t + 256], a1);
        }
        __threadfence();
        __syncthreads();
        if (t == 0) is_last = (atomicAdd(counter, 1.0f) == 127.0f);
        __syncthreads();
        if (!is_last) return;
        __threadfence();
        for (int which = 0; which < 2; ++which) {
            const float* v = which ? v2 : v1;
            const float* z = which ? z2 : z1;
            const int R = which ? 512 : 1536;
            float n1 = 0.f;
            for (int i = t; i < R; i += 256) { float q = v[i]; n1 += q * q; }
            red[t] = n1; __syncthreads();
            for (int off = 128; off > 0; off >>= 1) { if (t < off) red[t] += red[t + off]; __syncthreads(); }
            n1 = red[0]; __syncthreads();
            float n2 = 0.f;
            for (int i = t; i < 512; i += 256) { float q = z[i]; n2 += q * q; }
            red[t] = n2; __syncthreads();
            for (int off = 128; off > 0; off >>= 1) { if (t < off) red[t] += red[t + off]; __syncthreads(); }
            if (t == 0) scales[which] = (which ? so[0] : sq[0]) * sqrtf(n1 / red[0]);
            __syncthreads();
        }
        return;
    }

    // ---- gemm (double-buffered) ----
    const int bid = blockIdx.x - 128;
    const int lane = t & 63, w = t >> 6;
    const int wm = w >> 1, wn = w & 1, lg = lane >> 4, li = lane & 15;
    const int m0 = (bid / 24) * 128, n0 = (bid % 24) * 64;
    f32x4 acc[4][2] = {};

    auto STAGE = [&](int ks, int buf) {
        const int k0 = ks * 64;
#pragma unroll
        for (int i = 0; i < 4; ++i) {
            int j = w * 4 + i;
            int kc = j >> 1, mh = (j & 1) * 64;
            gload16(&A[(size_t)(m0 + mh + lane) * K + k0 + kc * 8], &As[buf][(kc * 128 + mh) * 8]);
        }
#pragma unroll
        for (int i = 0; i < 2; ++i) {
            int kc = w * 2 + i;
            gload16(&B[(size_t)(n0 + lane) * K + k0 + kc * 8], &Bs[buf][(kc * 64) * 8]);
        }
    };

    STAGE(0, 0);
    __syncthreads();
    int cur = 0;
    for (int ks = 0; ks < K / 64; ++ks) {
        if (ks < K / 64 - 1) STAGE(ks + 1, cur ^ 1);   // async, drains at the barrier
#pragma unroll
        for (int kw = 0; kw < 2; ++kw) {
            bf16x8 af[4], bf[2];
#pragma unroll
            for (int mi = 0; mi < 4; ++mi)
                af[mi] = *(const bf16x8*)&As[cur][((kw * 4 + lg) * 128 + wm * 64 + mi * 16 + li) * 8];
#pragma unroll
            for (int ni = 0; ni < 2; ++ni)
                bf[ni] = *(const bf16x8*)&Bs[cur][((kw * 4 + lg) * 64 + wn * 32 + ni * 16 + li) * 8];
#pragma unroll
            for (int mi = 0; mi < 4; ++mi)
#pragma unroll
                for (int ni = 0; ni < 2; ++ni)
                    acc[mi][ni] = mfma16(af[mi], bf[ni], acc[mi][ni]);
        }
        __syncthreads();
        cur ^= 1;
    }
    ushort_t* vT = qkv + (size_t)2 * BATCH * HEADS * SEQ * DH;
    if (n0 >= 1024) {
#pragma unroll
        for (int mi = 0; mi < 4; ++mi) {
            int base = m0 + wm * 64 + mi * 16 + lg * 4;
            int bb = base >> 11, ss = base & 2047;
#pragma unroll
            for (int ni = 0; ni < 2; ++ni) {
                int n = n0 + wn * 32 + ni * 16 + li;
                int h = (n >> 6) & 7, d0 = n & 63;
                ushort4 o;
                o.x = f2bf(acc[mi][ni][0]); o.y = f2bf(acc[mi][ni][1]);
                o.z = f2bf(acc[mi][ni][2]); o.w = f2bf(acc[mi][ni][3]);
                *(ushort4*)&vT[((size_t)((bb * HEADS + h) * DH) + d0) * SEQ + ss] = o;
            }
        }
    } else {
#pragma unroll
        for (int mi = 0; mi < 4; ++mi)
#pragma unroll
            for (int r = 0; r < 4; ++r) {
                int row = m0 + wm * 64 + mi * 16 + lg * 4 + r;
                int bb = row >> 11, ss = row & 2047;
#pragma unroll
                for (int ni = 0; ni < 2; ++ni) {
                    int n = n0 + wn * 32 + ni * 16 + li;
                    int which = n >> 9, h = (n >> 6) & 7, d0 = n & 63;
                    qkv[(size_t)which * (BATCH * HEADS * SEQ * DH) +
                        ((size_t)((bb * HEADS + h) * SEQ) + ss) * DH + d0] = f2bf(acc[mi][ni][r]);
                }
            }
    }
}

// ---------------- GEMM2: 64x64 tile, dbuf async staging, 512 blocks ---------------------
__global__ __launch_bounds__(256) void gemm_bt_out(const ushort_t* __restrict__ A,
                                                   const ushort_t* __restrict__ B,
                                                   const float* __restrict__ scales,
                                                   const float* __restrict__ bias,
                                                   float* __restrict__ C) {
    constexpr int K = INNER;
    __shared__ ushort_t As[2][8 * 64 * 8];
    __shared__ ushort_t Bs[2][8 * 64 * 8];
    const int t = threadIdx.x, lane = t & 63, w = t >> 6;
    const int wm = w >> 1, wn = w & 1, lg = lane >> 4, li = lane & 15;
    const int m0 = blockIdx.y * 64, n0 = blockIdx.x * 64;
    f32x4 acc[2][2] = {};

    auto STAGE = [&](int ks, int buf) {
        const int k0 = ks * 64;
#pragma unroll
        for (int i = 0; i < 2; ++i) {
            int kc = w * 2 + i;
            gload16(&A[(size_t)(m0 + lane) * K + k0 + kc * 8], &As[buf][(kc * 64) * 8]);
            gload16(&B[(size_t)(n0 + lane) * K + k0 + kc * 8], &Bs[buf][(kc * 64) * 8]);
        }
    };

    STAGE(0, 0);
    __syncthreads();
    int cur = 0;
    for (int ks = 0; ks < K / 64; ++ks) {
        if (ks < K / 64 - 1) STAGE(ks + 1, cur ^ 1);
#pragma unroll
        for (int kw = 0; kw < 2; ++kw) {
            bf16x8 af[2], bf[2];
#pragma unroll
            for (int mi = 0; mi < 2; ++mi)
                af[mi] = *(const bf16x8*)&As[cur][((kw * 4 + lg) * 64 + wm * 32 + mi * 16 + li) * 8];
#pragma unroll
            for (int ni = 0; ni < 2; ++ni)
                bf[ni] = *(const bf16x8*)&Bs[cur][((kw * 4 + lg) * 64 + wn * 32 + ni * 16 + li) * 8];
#pragma unroll
            for (int mi = 0; mi < 2; ++mi)
#pragma unroll
                for (int ni = 0; ni < 2; ++ni)
                    acc[mi][ni] = mfma16(af[mi], bf[ni], acc[mi][ni]);
        }
        __syncthreads();
        cur ^= 1;
    }
    const float sc = scales[0] * scales[1];
#pragma unroll
    for (int mi = 0; mi < 2; ++mi)
#pragma unroll
        for (int r = 0; r < 4; ++r) {
            int row = m0 + wm * 32 + mi * 16 + lg * 4 + r;
#pragma unroll
            for (int ni = 0; ni < 2; ++ni) {
                int n = n0 + wn * 32 + ni * 16 + li;
                C[(size_t)row * INNER + n] = acc[mi][ni][r] * sc + bias[n];
            }
        }
}

// ---------------- flash attention: swapped-QK MFMA, no-max softmax, split-KV, async dbuf
__global__ __launch_bounds__(512) void attn_mfma_kernel(const ushort_t* __restrict__ qkv,
                                                        const float* __restrict__ temp,
                                                        const float* __restrict__ scales,
                                                        ushort_t* __restrict__ attn_out) {
    __shared__ ushort_t kvbuf[2 * 4 * 4096];   // 64 KB: [buf][K0,K1,V0,V1]
    __shared__ ushort_t Pl[2 * 4096];          // 16 KB (den overlays after loop)
    const int t    = threadIdx.x;
    const int lane = t & 63, w = t >> 6;
    const int g    = w >> 2, wl = w & 3;
    const int lg   = lane >> 4, li = lane & 15;
    const int bh   = blockIdx.x >> 5;
    const int i0   = (blockIdx.x & 31) * 64;
    const ushort_t* qp  = qkv;
    const ushort_t* kp  = qkv + (size_t)BATCH * HEADS * SEQ * DH;
    const ushort_t* vTp = kp  + (size_t)BATCH * HEADS * SEQ * DH;  // [bh][d][s]
    const ushort_t* kp_bh  = kp  + (size_t)bh * SEQ * DH;
    const ushort_t* vTp_bh = vTp + (size_t)bh * DH * SEQ;
    const float s0 = scales[0];
    const float st = expf(temp[0]) * s0 * s0 * 1.44269504088896340736f;  // fold log2(e)

    ushort_t* Pb = Pl + g * 4096;
    const int srw = lane >> 3;                    // row within 8-row stripe
    const int sc  = (lane & 7) ^ srw;             // inverse-swizzled source chunk

    bf16x8 aQ[2];
#pragma unroll
    for (int c = 0; c < 2; ++c) {
        u16x8 qv = *(const u16x8*)&qp[((size_t)bh * SEQ + i0 + 16 * wl + li) * DH + 32 * c + lg * 8];
        u16x8 r;
#pragma unroll
        for (int j = 0; j < 8; ++j) r[j] = f2bf(bf2f(qv[j]) * st);
        aQ[c] = __builtin_bit_cast(bf16x8, r);
    }

    float lsum = 0.f;                 // per-lane: q = i0+16*wl+li
    f32x4 oacc[4] = {};
    const int qi = i0 + 16 * wl + li;

    auto STAGE = [&](int jtn, int tbuf) {
#pragma unroll
        for (int i = 0; i < 4; ++i) {
            const int sid = i * 8 + w;
            const int bsel = sid >> 3;            // 0,1: K tiles; 2,3: V tiles
            const int srow8 = sid & 7;
            const int row = srow8 * 8 + srw;
            const ushort_t* gsrc;
            if (bsel < 2)
                gsrc = kp_bh + (size_t)(jtn * 128 + bsel * 64 + row) * DH + sc * 8;
            else
                gsrc = vTp_bh + (size_t)row * SEQ + jtn * 128 + (bsel - 2) * 64 + sc * 8;
            gload16(gsrc, &kvbuf[tbuf * 16384 + bsel * 4096 + srow8 * 512]);
        }
    };

    STAGE(0, 0);
    __syncthreads();

    int cur = 0;
    for (int jt = 0; jt < SEQ / 128; ++jt) {
        if (jt < SEQ / 128 - 1) STAGE(jt + 1, cur ^ 1);   // async, drains at barrier
        const ushort_t* Kb = kvbuf + cur * 16384 + g * 4096;
        const ushort_t* Vb = kvbuf + cur * 16384 + 8192 + g * 4096;
        const int j0 = jt * 128 + g * 64;

        // S^T = K Q^T : s[kc][r] = S[k = j0+kc*16+lg*4+r][q = qi]
        f32x4 s[4];
        __builtin_amdgcn_s_setprio(1);
#pragma unroll
        for (int kc = 0; kc < 4; ++kc) {
            bf16x8 b0 = ld_frag(Kb, kc * 16 + li, lg * 8);
            bf16x8 b1 = ld_frag(Kb, kc * 16 + li, 32 + lg * 8);
            f32x4 z = {0.f, 0.f, 0.f, 0.f};
            z = mfma16(b0, aQ[0], z);      // A = K fragment, B = Q fragment
            z = mfma16(b1, aQ[1], z);
            s[kc] = z;
        }
        __builtin_amdgcn_s_setprio(0);
        // p = masked ? 0 : exp2(s); pack 4 consecutive k per ds_write_b64
        const bool need_mask = (j0 == i0) || (j0 == i0 - 64);
#pragma unroll
        for (int kc = 0; kc < 4; ++kc) {
            float p0, p1, p2, p3;
            if (need_mask) {
                int kjb = j0 + kc * 16 + lg * 4;
                p0 = ((unsigned)(qi - kjb - 0) < (unsigned)WIN) ? 0.f : fast_exp2(s[kc][0]);
                p1 = ((unsigned)(qi - kjb - 1) < (unsigned)WIN) ? 0.f : fast_exp2(s[kc][1]);
                p2 = ((unsigned)(qi - kjb - 2) < (unsigned)WIN) ? 0.f : fast_exp2(s[kc][2]);
                p3 = ((unsigned)(qi - kjb - 3) < (unsigned)WIN) ? 0.f : fast_exp2(s[kc][3]);
            } else {
                p0 = fast_exp2(s[kc][0]); p1 = fast_exp2(s[kc][1]);
                p2 = fast_exp2(s[kc][2]); p3 = fast_exp2(s[kc][3]);
            }
            lsum += (p0 + p1) + (p2 + p3);
            ushort4 o;
            o.x = f2bf(p0); o.y = f2bf(p1); o.z = f2bf(p2); o.w = f2bf(p3);
            *(ushort4*)&Pb[swz_idx(16 * wl + li, kc * 16 + lg * 4)] = o;
        }
        // PV: O += P V
        bf16x8 aP[2];
#pragma unroll
        for (int c = 0; c < 2; ++c) aP[c] = ld_frag(Pb, 16 * wl + li, c * 32 + lg * 8);
        __builtin_amdgcn_s_setprio(1);
#pragma unroll
        for (int tt = 0; tt < 4; ++tt) {
            bf16x8 b0 = ld_frag(Vb, tt * 16 + li, lg * 8);
            bf16x8 b1 = ld_frag(Vb, tt * 16 + li, 32 + lg * 8);
            oacc[tt] = mfma16(aP[0], b0, oacc[tt]);
            oacc[tt] = mfma16(aP[1], b1, oacc[tt]);
        }
        __builtin_amdgcn_s_setprio(0);
        __syncthreads();
        cur ^= 1;
    }

    // full denominator for q = qi: reduce across the 4 lg groups
    lsum += __shfl_xor(lsum, 16, 64);
    lsum += __shfl_xor(lsum, 32, 64);
    float* den    = (float*)Pl;           // [2][64] overlay (P no longer read)
    float* O_part = (float*)kvbuf;        // 64 x 68 f32 (padded: no bank conflict)
    if (lg == 0) den[g * 64 + 16 * wl + li] = lsum;
    if (g == 1) {
#pragma unroll
        for (int r = 0; r < 4; ++r) {
            int row = 16 * wl + lg * 4 + r;
#pragma unroll
            for (int tt = 0; tt < 4; ++tt)
                O_part[row * 68 + tt * 16 + li] = oacc[tt][r];
        }
    }
    __syncthreads();
    if (g == 0) {
        const int b_ = bh >> 3, h = bh & 7;
#pragma unroll
        for (int r = 0; r < 4; ++r) {
            int row = 16 * wl + lg * 4 + r;
            float inv = 1.0f / (den[row] + den[64 + row]);
            size_t base = ((size_t)(b_ * SEQ + i0 + row)) * INNER + h * DH;
#pragma unroll
            for (int tt = 0; tt < 4; ++tt)
                attn_out[base + tt * 16 + li] =
                    f2bf((oacc[tt][r] + O_part[row * 68 + tt * 16 + li]) * inv);
        }
    }
}

extern "C" void kernel_launch(void* const* d_in, const int* in_sizes, int n_in,
                              void* d_out, int out_size, void* d_ws, size_t ws_size,
                              hipStream_t stream) {
    const float* x     = (const float*)d_in[0];
    const float* W_qkv = (const float*)d_in[1];
    const float* u_qkv = (const float*)d_in[2];
    const float* s_qkv = (const float*)d_in[3];
    const float* W_out = (const float*)d_in[4];
    const float* b_out = (const float*)d_in[5];
    const float* u_out = (const float*)d_in[6];
    const float* s_out = (const float*)d_in[7];
    const float* temp  = (const float*)d_in[8];
    float* out = (float*)d_out;

    float* scales  = (float*)d_ws;        // 2
    float* v1      = scales + 64;         // 1536
    float* v2      = v1 + 1536;           // 512
    float* z1      = v2 + 512;            // 512   <- zbuf base (z1,z2,counter zeroed by k1)
    float* z2      = z1 + 512;            // 512
    float* counter = z1 + 1024;           // 1
    ushort_t* xb    = (ushort_t*)((char*)d_ws + 16384);
    ushort_t* wqb   = xb + (size_t)2097152;
    ushort_t* wob   = wqb + (size_t)786432;
    ushort_t* qkvb  = wob + (size_t)262144;
    ushort_t* attnb = qkvb + (size_t)6291456;

    fused_cast_sn1<<<dim3(2048), dim3(256), 0, stream>>>(x, W_qkv, W_out, u_qkv, u_out,
                                                         xb, wqb, wob, z1, v1, v2);
    gemm_qkv_sn<<<dim3(896), dim3(256), 0, stream>>>(xb, wqb, qkvb, W_qkv, W_out, v1, v2,
                                                     z1, z2, counter, s_qkv, s_out, scales);
    attn_mfma_kernel<<<dim3(512), dim3(512), 0, stream>>>(qkvb, temp, scales, attnb);
    gemm_bt_out<<<dim3(8, 64), dim3(256), 0, stream>>>(attnb, wob, scales, b_out, out);
}